// Round 2
// baseline (261.846 us; speedup 1.0000x reference)
//
#include <hip/hip_runtime.h>
#include <math.h>

#define RES 2048
#define NB  256

// ---------------------------------------------------------------------------
// Kernel 1: per-beam, per-axis complex tables.
//   Ux[b,i] = (re + i*im) * exp(-(x_i-x0)^2/sig^2) * exp(i*kx*x_i)
//   Vy[b,j] =               exp(-(y_j-y0)^2/sig^2) * exp(i*ky*y_j)
// so that E[i,j] = sum_b Ux[b,i] * Vy[b,j]  (complex), out = |E|^2.
// ---------------------------------------------------------------------------
__global__ void beam_tables(const float* __restrict__ theta,
                            const float* __restrict__ reA,
                            const float* __restrict__ imA,
                            const float* __restrict__ x0A,
                            const float* __restrict__ y0A,
                            const float* __restrict__ lsA,
                            const float* __restrict__ X,
                            const float* __restrict__ Y,
                            float* __restrict__ UxRe, float* __restrict__ UxIm,
                            float* __restrict__ VyRe, float* __restrict__ VyIm)
{
    const int b = blockIdx.x;
    const float th  = theta[b];
    const float re  = reA[b], im = imA[b];
    const float px  = x0A[b], py = y0A[b];
    const float sig = expf(lsA[b]) + 0.001f;
    const float is2 = 1.0f / (sig * sig);
    const float kx  = 50.0f * cosf(th);
    const float ky  = 50.0f * sinf(th);

    for (int i = threadIdx.x; i < RES; i += blockDim.x) {
        const float xv = X[(size_t)i * RES]; // X[i][0] = x_i (indexing='ij')
        const float yv = Y[i];               // Y[0][j] = y_j
        float sx, cx, sy, cy;
        sincosf(kx * xv, &sx, &cx);
        sincosf(ky * yv, &sy, &cy);
        const float dx = xv - px, dy = yv - py;
        const float ex = expf(-(dx * dx) * is2);
        const float ey = expf(-(dy * dy) * is2);
        UxRe[b * RES + i] = ex * (re * cx - im * sx);
        UxIm[b * RES + i] = ex * (re * sx + im * cx);
        VyRe[b * RES + i] = ey * cy;
        VyIm[b * RES + i] = ey * sy;
    }
}

// ---------------------------------------------------------------------------
// Kernel 2: complex GEMM  E = Ux^T * Vy  (M=N=2048, K=256), out = |E|^2.
// Double-buffered LDS + register prefetch (T14 async-STAGE split):
//   per k-step: issue next-tile global loads -> compute on buf[cur] ->
//   ds_write regs into buf[cur^1] -> ONE barrier.
// BM=128, BN=64, BK=16, 256 threads, per-thread 8x4 complex micro-tile.
// ---------------------------------------------------------------------------
#define BM 128
#define BN 64
#define BK 16
#define TM 8
#define TN 4
#define NSTEP (NB / BK)

__global__ __launch_bounds__(256) void ewald_gemm(
    const float* __restrict__ UxRe, const float* __restrict__ UxIm,
    const float* __restrict__ VyRe, const float* __restrict__ VyIm,
    float* __restrict__ out)
{
    __shared__ float As_re[2][BK][BM];
    __shared__ float As_im[2][BK][BM];
    __shared__ float Bs_re[2][BK][BN];
    __shared__ float Bs_im[2][BK][BN];

    const int t  = threadIdx.x;
    const int tx = t & 15;   // N direction: 16 * TN(4) = 64
    const int ty = t >> 4;   // M direction: 16 * TM(8) = 128
    const int m0 = blockIdx.y * BM;
    const int n0 = blockIdx.x * BN;

    // staging maps
    const int arow = t >> 5;        // 0..7  (A row has 32 float4)
    const int acol = (t & 31) * 4;
    const int brow = t >> 4;        // 0..15 (B row has 16 float4)
    const int bcol = (t & 15) * 4;

    float accRe[TM][TN] = {};
    float accIm[TM][TN] = {};

    // ---- prologue: stage k-tile 0 straight into buffer 0 ----
    {
        const size_t a0 = (size_t)arow * RES + m0 + acol;
        const size_t a1 = (size_t)(arow + 8) * RES + m0 + acol;
        const size_t b0 = (size_t)brow * RES + n0 + bcol;
        *(float4*)&As_re[0][arow][acol]     = *(const float4*)&UxRe[a0];
        *(float4*)&As_re[0][arow + 8][acol] = *(const float4*)&UxRe[a1];
        *(float4*)&As_im[0][arow][acol]     = *(const float4*)&UxIm[a0];
        *(float4*)&As_im[0][arow + 8][acol] = *(const float4*)&UxIm[a1];
        *(float4*)&Bs_re[0][brow][bcol]     = *(const float4*)&VyRe[b0];
        *(float4*)&Bs_im[0][brow][bcol]     = *(const float4*)&VyIm[b0];
    }
    __syncthreads();

    for (int step = 0; step < NSTEP; ++step) {
        const int cur = step & 1;
        const bool has_next = (step + 1 < NSTEP);

        // ---- issue next tile's global loads (stay in flight over compute) ----
        float4 ra0, ra1, qa0, qa1, rb, qb;
        if (has_next) {
            const int k0 = (step + 1) * BK;
            const size_t a0 = (size_t)(k0 + arow) * RES + m0 + acol;
            const size_t a1 = (size_t)(k0 + arow + 8) * RES + m0 + acol;
            const size_t b0 = (size_t)(k0 + brow) * RES + n0 + bcol;
            ra0 = *(const float4*)&UxRe[a0];
            ra1 = *(const float4*)&UxRe[a1];
            qa0 = *(const float4*)&UxIm[a0];
            qa1 = *(const float4*)&UxIm[a1];
            rb  = *(const float4*)&VyRe[b0];
            qb  = *(const float4*)&VyIm[b0];
        }

        // ---- compute on buf[cur] ----
        #pragma unroll
        for (int kk = 0; kk < BK; ++kk) {
            float ar[TM], ai[TM], br[TN], bi[TN];
            *(float4*)&ar[0] = *(const float4*)&As_re[cur][kk][ty * TM];
            *(float4*)&ar[4] = *(const float4*)&As_re[cur][kk][ty * TM + 4];
            *(float4*)&ai[0] = *(const float4*)&As_im[cur][kk][ty * TM];
            *(float4*)&ai[4] = *(const float4*)&As_im[cur][kk][ty * TM + 4];
            *(float4*)&br[0] = *(const float4*)&Bs_re[cur][kk][tx * TN];
            *(float4*)&bi[0] = *(const float4*)&Bs_im[cur][kk][tx * TN];
            #pragma unroll
            for (int mi = 0; mi < TM; ++mi) {
                #pragma unroll
                for (int ni = 0; ni < TN; ++ni) {
                    accRe[mi][ni] += ar[mi] * br[ni] - ai[mi] * bi[ni];
                    accIm[mi][ni] += ar[mi] * bi[ni] + ai[mi] * br[ni];
                }
            }
        }

        // ---- write prefetched regs into the other buffer; one barrier ----
        if (has_next) {
            const int nxt = cur ^ 1;
            *(float4*)&As_re[nxt][arow][acol]     = ra0;
            *(float4*)&As_re[nxt][arow + 8][acol] = ra1;
            *(float4*)&As_im[nxt][arow][acol]     = qa0;
            *(float4*)&As_im[nxt][arow + 8][acol] = qa1;
            *(float4*)&Bs_re[nxt][brow][bcol]     = rb;
            *(float4*)&Bs_im[nxt][brow][bcol]     = qb;
            __syncthreads();
        }
    }

    // ---- epilogue: out = |E|^2, float4 stores ----
    #pragma unroll
    for (int mi = 0; mi < TM; ++mi) {
        float4 o;
        o.x = accRe[mi][0] * accRe[mi][0] + accIm[mi][0] * accIm[mi][0];
        o.y = accRe[mi][1] * accRe[mi][1] + accIm[mi][1] * accIm[mi][1];
        o.z = accRe[mi][2] * accRe[mi][2] + accIm[mi][2] * accIm[mi][2];
        o.w = accRe[mi][3] * accRe[mi][3] + accIm[mi][3] * accIm[mi][3];
        *(float4*)&out[(size_t)(m0 + ty * TM + mi) * RES + n0 + tx * TN] = o;
    }
}

// ---------------------------------------------------------------------------
// Fallback: direct brute force (only used if ws_size < 8 MB).
// ---------------------------------------------------------------------------
__global__ __launch_bounds__(256) void ewald_direct(
    const float* __restrict__ theta, const float* __restrict__ reA,
    const float* __restrict__ imA, const float* __restrict__ x0A,
    const float* __restrict__ y0A, const float* __restrict__ lsA,
    const float* __restrict__ X, const float* __restrict__ Y,
    float* __restrict__ out)
{
    __shared__ float kxs[NB], kys[NB], res[NB], ims[NB], pxs[NB], pys[NB], is2s[NB];
    const int t = threadIdx.x;
    if (t < NB) {
        const float th  = theta[t];
        const float sig = expf(lsA[t]) + 0.001f;
        kxs[t] = 50.0f * cosf(th);
        kys[t] = 50.0f * sinf(th);
        res[t] = reA[t];
        ims[t] = imA[t];
        pxs[t] = x0A[t];
        pys[t] = y0A[t];
        is2s[t] = 1.0f / (sig * sig);
    }
    __syncthreads();

    const size_t npix = (size_t)RES * RES;
    for (size_t idx = (size_t)blockIdx.x * blockDim.x + t; idx < npix;
         idx += (size_t)gridDim.x * blockDim.x) {
        const float xv = X[idx], yv = Y[idx];
        float er = 0.f, ei = 0.f;
        for (int b = 0; b < NB; ++b) {
            const float dx = xv - pxs[b], dy = yv - pys[b];
            const float env = __expf(-(dx * dx + dy * dy) * is2s[b]);
            const float ph = kxs[b] * xv + kys[b] * yv;
            float s, c;
            __sincosf(ph, &s, &c);
            er += env * (res[b] * c - ims[b] * s);
            ei += env * (res[b] * s + ims[b] * c);
        }
        out[idx] = er * er + ei * ei;
    }
}

// ---------------------------------------------------------------------------
extern "C" void kernel_launch(void* const* d_in, const int* in_sizes, int n_in,
                              void* d_out, int out_size, void* d_ws, size_t ws_size,
                              hipStream_t stream) {
    const float* theta = (const float*)d_in[0];
    const float* reA   = (const float*)d_in[1];
    const float* imA   = (const float*)d_in[2];
    const float* x0A   = (const float*)d_in[3];
    const float* y0A   = (const float*)d_in[4];
    const float* lsA   = (const float*)d_in[5];
    const float* X     = (const float*)d_in[6];
    const float* Y     = (const float*)d_in[7];
    float* out = (float*)d_out;

    const size_t tbl = (size_t)NB * RES;               // elements per table
    const size_t need = 4 * tbl * sizeof(float);       // 8 MB

    if (ws_size >= need) {
        float* UxRe = (float*)d_ws;
        float* UxIm = UxRe + tbl;
        float* VyRe = UxIm + tbl;
        float* VyIm = VyRe + tbl;

        beam_tables<<<NB, 256, 0, stream>>>(theta, reA, imA, x0A, y0A, lsA,
                                            X, Y, UxRe, UxIm, VyRe, VyIm);

        dim3 grid(RES / BN, RES / BM); // 32 x 16 = 512 blocks
        ewald_gemm<<<grid, 256, 0, stream>>>(UxRe, UxIm, VyRe, VyIm, out);
    } else {
        ewald_direct<<<2048, 256, 0, stream>>>(theta, reA, imA, x0A, y0A, lsA,
                                               X, Y, out);
    }
}

// Round 3
// 194.669 us; speedup vs baseline: 1.3451x; 1.3451x over previous
//
#include <hip/hip_runtime.h>
#include <math.h>

#define RES 2048
#define NB  256

// ---------------------------------------------------------------------------
// Kernel 1: per-beam, per-axis complex tables.
//   Ux[b,i] = (re + i*im) * exp(-(x_i-x0)^2/sig^2) * exp(i*kx*x_i)
//   Vy[b,j] =               exp(-(y_j-y0)^2/sig^2) * exp(i*ky*y_j)
// so that E[i,j] = sum_b Ux[b,i] * Vy[b,j]  (complex), out = |E|^2.
// ---------------------------------------------------------------------------
__global__ void beam_tables(const float* __restrict__ theta,
                            const float* __restrict__ reA,
                            const float* __restrict__ imA,
                            const float* __restrict__ x0A,
                            const float* __restrict__ y0A,
                            const float* __restrict__ lsA,
                            const float* __restrict__ X,
                            const float* __restrict__ Y,
                            float* __restrict__ UxRe, float* __restrict__ UxIm,
                            float* __restrict__ VyRe, float* __restrict__ VyIm)
{
    const int b = blockIdx.x;
    const float th  = theta[b];
    const float re  = reA[b], im = imA[b];
    const float px  = x0A[b], py = y0A[b];
    const float sig = expf(lsA[b]) + 0.001f;
    const float is2 = 1.0f / (sig * sig);
    const float kx  = 50.0f * cosf(th);
    const float ky  = 50.0f * sinf(th);

    for (int i = threadIdx.x; i < RES; i += blockDim.x) {
        const float xv = X[(size_t)i * RES]; // X[i][0] = x_i (indexing='ij')
        const float yv = Y[i];               // Y[0][j] = y_j
        float sx, cx, sy, cy;
        sincosf(kx * xv, &sx, &cx);
        sincosf(ky * yv, &sy, &cy);
        const float dx = xv - px, dy = yv - py;
        const float ex = expf(-(dx * dx) * is2);
        const float ey = expf(-(dy * dy) * is2);
        UxRe[b * RES + i] = ex * (re * cx - im * sx);
        UxIm[b * RES + i] = ex * (re * sx + im * cx);
        VyRe[b * RES + i] = ey * cy;
        VyIm[b * RES + i] = ey * sy;
    }
}

// ---------------------------------------------------------------------------
// Kernel 2: complex GEMM  E = Ux^T * Vy  (M=N=2048, K=256), out = |E|^2.
// T3 "minimum 2-phase" schedule with global_load_lds (zero staging VGPRs):
//   per k-step: issue async global->LDS loads of tile k+1 into buf^1,
//   compute on buf, ONE __syncthreads (vmcnt(0)+lgkmcnt(0) drain), swap.
// BM=128, BN=64, BK=16, 256 threads (4 waves), per-thread 8x4 complex tile.
// ---------------------------------------------------------------------------
#define BM 128
#define BN 64
#define BK 16
#define TM 8
#define TN 4
#define NSTEP (NB / BK)

#define AS1 __attribute__((address_space(1)))
#define AS3 __attribute__((address_space(3)))

__device__ __forceinline__ void g2l16(const void* g, void* l) {
    // async 16B/lane global->LDS; LDS dest = wave-uniform base + lane*16
    __builtin_amdgcn_global_load_lds((const AS1 void*)g, (AS3 void*)l, 16, 0, 0);
}

__global__ __launch_bounds__(256) void ewald_gemm(
    const float* __restrict__ UxRe, const float* __restrict__ UxIm,
    const float* __restrict__ VyRe, const float* __restrict__ VyIm,
    float* __restrict__ out)
{
    __shared__ float As_re[2][BK][BM];
    __shared__ float As_im[2][BK][BM];
    __shared__ float Bs_re[2][BK][BN];
    __shared__ float Bs_im[2][BK][BN];

    const int t    = threadIdx.x;
    const int lane = t & 63;
    const int wave = t >> 6;          // 0..3
    const int tx = t & 15;            // N direction: 16 * TN(4) = 64
    const int ty = t >> 4;            // M direction: 16 * TM(8) = 128
    const int m0 = blockIdx.y * BM;
    const int n0 = blockIdx.x * BN;

    // Per-wave staging: 24 chunks of 1024B (1 wave-load each):
    //   c in [0,8)  : A_re rows 2c..2c+1   (row = 128 floats = 512B)
    //   c in [8,16) : A_im rows 2(c-8)..   ditto
    //   c in [16,20): B_re rows 4(c-16)..  (row = 64 floats = 256B)
    //   c in [20,24): B_im rows 4(c-20)..
    // Lane layout matches LDS-linear order (base + lane*16).
    const int aSub = lane >> 5;            // 0..1
    const int aCol = (lane & 31) * 4;      // 0..124
    const int bSub = lane >> 4;            // 0..3
    const int bCol = (lane & 15) * 4;      // 0..60

    #define STAGE(bf, k0)                                                     \
    do {                                                                      \
        for (int c = wave; c < 24; c += 4) {                                  \
            if (c < 8) {                                                      \
                const int r = 2 * c;                                          \
                g2l16(&UxRe[(size_t)((k0) + r + aSub) * RES + m0 + aCol],     \
                      &As_re[bf][r][0]);                                      \
            } else if (c < 16) {                                              \
                const int r = 2 * (c - 8);                                    \
                g2l16(&UxIm[(size_t)((k0) + r + aSub) * RES + m0 + aCol],     \
                      &As_im[bf][r][0]);                                      \
            } else if (c < 20) {                                              \
                const int r = 4 * (c - 16);                                   \
                g2l16(&VyRe[(size_t)((k0) + r + bSub) * RES + n0 + bCol],     \
                      &Bs_re[bf][r][0]);                                      \
            } else {                                                          \
                const int r = 4 * (c - 20);                                   \
                g2l16(&VyIm[(size_t)((k0) + r + bSub) * RES + n0 + bCol],     \
                      &Bs_im[bf][r][0]);                                      \
            }                                                                 \
        }                                                                     \
    } while (0)

    float accRe[TM][TN] = {};
    float accIm[TM][TN] = {};

    // ---- prologue: stage tile 0 into buffer 0 ----
    STAGE(0, 0);
    __syncthreads();   // vmcnt(0) drain -> tile 0 resident

    int cur = 0;
    for (int step = 0; step < NSTEP; ++step) {
        // ---- issue next tile's async loads into the other buffer ----
        if (step + 1 < NSTEP) {
            const int k0n = (step + 1) * BK;
            STAGE(cur ^ 1, k0n);
        }

        // ---- compute on buf[cur] ----
        #pragma unroll
        for (int kk = 0; kk < BK; ++kk) {
            float ar[TM], ai[TM], br[TN], bi[TN];
            *(float4*)&ar[0] = *(const float4*)&As_re[cur][kk][ty * TM];
            *(float4*)&ar[4] = *(const float4*)&As_re[cur][kk][ty * TM + 4];
            *(float4*)&ai[0] = *(const float4*)&As_im[cur][kk][ty * TM];
            *(float4*)&ai[4] = *(const float4*)&As_im[cur][kk][ty * TM + 4];
            *(float4*)&br[0] = *(const float4*)&Bs_re[cur][kk][tx * TN];
            *(float4*)&bi[0] = *(const float4*)&Bs_im[cur][kk][tx * TN];
            #pragma unroll
            for (int mi = 0; mi < TM; ++mi) {
                #pragma unroll
                for (int ni = 0; ni < TN; ++ni) {
                    accRe[mi][ni] += ar[mi] * br[ni] - ai[mi] * bi[ni];
                    accIm[mi][ni] += ar[mi] * bi[ni] + ai[mi] * br[ni];
                }
            }
        }

        // ---- ONE barrier: drains vmcnt (next tile resident) and
        //      guarantees all waves are done reading buf[cur] ----
        __syncthreads();
        cur ^= 1;
    }

    // ---- epilogue: out = |E|^2, float4 stores ----
    #pragma unroll
    for (int mi = 0; mi < TM; ++mi) {
        float4 o;
        o.x = accRe[mi][0] * accRe[mi][0] + accIm[mi][0] * accIm[mi][0];
        o.y = accRe[mi][1] * accRe[mi][1] + accIm[mi][1] * accIm[mi][1];
        o.z = accRe[mi][2] * accRe[mi][2] + accIm[mi][2] * accIm[mi][2];
        o.w = accRe[mi][3] * accRe[mi][3] + accIm[mi][3] * accIm[mi][3];
        *(float4*)&out[(size_t)(m0 + ty * TM + mi) * RES + n0 + tx * TN] = o;
    }
}

// ---------------------------------------------------------------------------
// Fallback: direct brute force (only used if ws_size < 8 MB).
// ---------------------------------------------------------------------------
__global__ __launch_bounds__(256) void ewald_direct(
    const float* __restrict__ theta, const float* __restrict__ reA,
    const float* __restrict__ imA, const float* __restrict__ x0A,
    const float* __restrict__ y0A, const float* __restrict__ lsA,
    const float* __restrict__ X, const float* __restrict__ Y,
    float* __restrict__ out)
{
    __shared__ float kxs[NB], kys[NB], res[NB], ims[NB], pxs[NB], pys[NB], is2s[NB];
    const int t = threadIdx.x;
    if (t < NB) {
        const float th  = theta[t];
        const float sig = expf(lsA[t]) + 0.001f;
        kxs[t] = 50.0f * cosf(th);
        kys[t] = 50.0f * sinf(th);
        res[t] = reA[t];
        ims[t] = imA[t];
        pxs[t] = x0A[t];
        pys[t] = y0A[t];
        is2s[t] = 1.0f / (sig * sig);
    }
    __syncthreads();

    const size_t npix = (size_t)RES * RES;
    for (size_t idx = (size_t)blockIdx.x * blockDim.x + t; idx < npix;
         idx += (size_t)gridDim.x * blockDim.x) {
        const float xv = X[idx], yv = Y[idx];
        float er = 0.f, ei = 0.f;
        for (int b = 0; b < NB; ++b) {
            const float dx = xv - pxs[b], dy = yv - pys[b];
            const float env = __expf(-(dx * dx + dy * dy) * is2s[b]);
            const float ph = kxs[b] * xv + kys[b] * yv;
            float s, c;
            __sincosf(ph, &s, &c);
            er += env * (res[b] * c - ims[b] * s);
            ei += env * (res[b] * s + ims[b] * c);
        }
        out[idx] = er * er + ei * ei;
    }
}

// ---------------------------------------------------------------------------
extern "C" void kernel_launch(void* const* d_in, const int* in_sizes, int n_in,
                              void* d_out, int out_size, void* d_ws, size_t ws_size,
                              hipStream_t stream) {
    const float* theta = (const float*)d_in[0];
    const float* reA   = (const float*)d_in[1];
    const float* imA   = (const float*)d_in[2];
    const float* x0A   = (const float*)d_in[3];
    const float* y0A   = (const float*)d_in[4];
    const float* lsA   = (const float*)d_in[5];
    const float* X     = (const float*)d_in[6];
    const float* Y     = (const float*)d_in[7];
    float* out = (float*)d_out;

    const size_t tbl = (size_t)NB * RES;               // elements per table
    const size_t need = 4 * tbl * sizeof(float);       // 8 MB

    if (ws_size >= need) {
        float* UxRe = (float*)d_ws;
        float* UxIm = UxRe + tbl;
        float* VyRe = UxIm + tbl;
        float* VyIm = VyRe + tbl;

        beam_tables<<<NB, 256, 0, stream>>>(theta, reA, imA, x0A, y0A, lsA,
                                            X, Y, UxRe, UxIm, VyRe, VyIm);

        dim3 grid(RES / BN, RES / BM); // 32 x 16 = 512 blocks
        ewald_gemm<<<grid, 256, 0, stream>>>(UxRe, UxIm, VyRe, VyIm, out);
    } else {
        ewald_direct<<<2048, 256, 0, stream>>>(theta, reA, imA, x0A, y0A, lsA,
                                               X, Y, out);
    }
}

// Round 4
// 30.709 us; speedup vs baseline: 8.5266x; 6.3391x over previous
//
#include <hip/hip_runtime.h>
#include <math.h>

#define RES 2048
#define NB  256

typedef _Float16 f16;
typedef _Float16 f16x8 __attribute__((ext_vector_type(8)));
typedef float    f32x16 __attribute__((ext_vector_type(16)));

#define AS1 __attribute__((address_space(1)))
#define AS3 __attribute__((address_space(3)))

__device__ __forceinline__ void g2l16(const void* g, void* l) {
    // async 16B/lane global->LDS; LDS dest = wave-uniform base + lane*16
    __builtin_amdgcn_global_load_lds((const AS1 void*)g, (AS3 void*)l, 16, 0, 0);
}

// ---------------------------------------------------------------------------
// Kernel 1: per-beam, per-axis complex tables, TRANSPOSED ([pos][beam]) and
// cast to fp16 so the GEMM can stage k-contiguous rows with global_load_lds.
//   A(i,b) = (re + i*im) * exp(-(x_i-x0)^2/s^2) * exp(i*kx*x_i)   (M side)
//   B(j,b) =               exp(-(y_j-y0)^2/s^2) * exp(i*ky*y_j)   (N side)
//   BImN = -BIm  (pre-negated plane so E_re = ARe.BRe + AIm.BImN)
// ---------------------------------------------------------------------------
__global__ void beam_tables_f16(const float* __restrict__ theta,
                                const float* __restrict__ reA,
                                const float* __restrict__ imA,
                                const float* __restrict__ x0A,
                                const float* __restrict__ y0A,
                                const float* __restrict__ lsA,
                                const float* __restrict__ X,
                                const float* __restrict__ Y,
                                f16* __restrict__ ARe, f16* __restrict__ AIm,
                                f16* __restrict__ BRe, f16* __restrict__ BIm,
                                f16* __restrict__ BImN)
{
    const int i = blockIdx.x;    // position index (both axes have RES entries)
    const int b = threadIdx.x;   // beam
    const float th  = theta[b];
    const float re  = reA[b], im = imA[b];
    const float px  = x0A[b], py = y0A[b];
    const float sig = expf(lsA[b]) + 0.001f;
    const float is2 = 1.0f / (sig * sig);
    const float kx  = 50.0f * cosf(th);
    const float ky  = 50.0f * sinf(th);

    const float xv = X[(size_t)i * RES];  // X[i][0] = x_i (indexing='ij')
    const float yv = Y[i];                // Y[0][j] = y_j

    float sx, cx, sy, cy;
    sincosf(kx * xv, &sx, &cx);
    sincosf(ky * yv, &sy, &cy);
    const float dx = xv - px, dy = yv - py;
    const float ex = expf(-dx * dx * is2);
    const float ey = expf(-dy * dy * is2);

    const int o = i * NB + b;
    ARe[o]  = (f16)(ex * (re * cx - im * sx));
    AIm[o]  = (f16)(ex * (re * sx + im * cx));
    const float br = ey * cy, bi = ey * sy;
    BRe[o]  = (f16)br;
    BIm[o]  = (f16)bi;
    BImN[o] = (f16)(-bi);
}

// ---------------------------------------------------------------------------
// Kernel 2: complex GEMM on matrix cores.
//   E[i,j] = sum_b A(i,b)*B(j,b);  out = |E|^2.
// mfma_f32_32x32x16_f16, BM=BN=128, BK=16, 512 threads (8 waves, 2Mx4N),
// wave tile 64x32 (2 C-tiles of 32x32, 2 accs each = 64 acc VGPR).
// LDS: [2 buf][5 planes][128 rows][16 f16] = 40 KB, double-buffered 2-phase
// with global_load_lds (zero staging VGPRs), one barrier per k-tile.
// Per k-tile per wave: 7 ds_read_b128 + 8 MFMA.
// ---------------------------------------------------------------------------
#define BM 128
#define BN 128
#define BK 16
#define NKT (NB / BK)          // 16
#define PLSTRIDE (BM * BK)     // elements per plane region (2048)
#define BUFSTRIDE (5 * PLSTRIDE)

__global__ __launch_bounds__(512) void ewald_mfma(
    const f16* __restrict__ ARe, const f16* __restrict__ AIm,
    const f16* __restrict__ BRe, const f16* __restrict__ BIm,
    const f16* __restrict__ BImN, float* __restrict__ out)
{
    __shared__ f16 sm[2][5][BM][BK];
    f16* const smBase = &sm[0][0][0][0];

    const int t    = threadIdx.x;
    const int lane = t & 63;
    const int wave = t >> 6;       // 0..7
    const int wm   = wave >> 2;    // 0..1 -> M offset 64
    const int wn   = wave & 3;     // 0..3 -> N offset 32
    const int la   = lane & 31;
    const int lg   = lane >> 5;

    // XCD-aware swizzle (256 blocks, 8 XCDs -> 32 contiguous per XCD)
    const int flat = blockIdx.x;
    const int swz  = (flat & 7) * 32 + (flat >> 3);
    const int m0   = (swz >> 4) * BM;
    const int n0   = (swz & 15) * BN;

    // ---- staging map: 20 wave-loads (1 KB each) per k-tile ----
    // q = plane*4 + chunk; plane 0..4 = {ARe,AIm,BRe,BIm,BImN}; chunk = 32 rows.
    // lane w covers row chunk*32 + (w>>1), k-half (w&1)*8.
    const f16* gsrc[3];
    int  ldso[3];
    bool qvalid[3];
    #pragma unroll
    for (int j = 0; j < 3; ++j) {
        const int q = wave + 8 * j;
        qvalid[j] = (q < 20);
        const int p = qvalid[j] ? (q >> 2) : 0;
        const int c = q & 3;
        const f16* tp = (p == 0) ? ARe : (p == 1) ? AIm
                       : (p == 2) ? BRe : (p == 3) ? BIm : BImN;
        const int rowbase = ((p < 2) ? m0 : n0) + c * 32 + (lane >> 1);
        gsrc[j] = tp + (size_t)rowbase * NB + (lane & 1) * 8;
        ldso[j] = p * PLSTRIDE + (c * 32) * BK;
    }

    #define STAGE(boff, kt)                                                   \
    do {                                                                      \
        _Pragma("unroll")                                                     \
        for (int j = 0; j < 3; ++j) {                                         \
            if (qvalid[j])                                                    \
                g2l16(gsrc[j] + (kt) * BK, smBase + (boff) + ldso[j]);        \
        }                                                                     \
    } while (0)

    // ---- fragment LDS element-offsets (within one buffer) ----
    const int offAR0 = 0 * PLSTRIDE + (wm * 64 +  0 + la) * BK + lg * 8;
    const int offAR1 = 0 * PLSTRIDE + (wm * 64 + 32 + la) * BK + lg * 8;
    const int offAI0 = 1 * PLSTRIDE + (wm * 64 +  0 + la) * BK + lg * 8;
    const int offAI1 = 1 * PLSTRIDE + (wm * 64 + 32 + la) * BK + lg * 8;
    const int offBR  = 2 * PLSTRIDE + (wn * 32 + la) * BK + lg * 8;
    const int offBI  = 3 * PLSTRIDE + (wn * 32 + la) * BK + lg * 8;
    const int offBN_ = 4 * PLSTRIDE + (wn * 32 + la) * BK + lg * 8;

    f32x16 accRe0 = (f32x16)0.0f, accIm0 = (f32x16)0.0f;
    f32x16 accRe1 = (f32x16)0.0f, accIm1 = (f32x16)0.0f;

    // ---- prologue: stage k-tile 0 into buffer 0 ----
    STAGE(0, 0);
    __syncthreads();

    for (int kt = 0; kt < NKT; ++kt) {
        const int boff = (kt & 1) * BUFSTRIDE;
        if (kt + 1 < NKT)
            STAGE(((kt + 1) & 1) * BUFSTRIDE, kt + 1);

        const f16* s = smBase + boff;
        const f16x8 aR0 = *(const f16x8*)(s + offAR0);
        const f16x8 aR1 = *(const f16x8*)(s + offAR1);
        const f16x8 aI0 = *(const f16x8*)(s + offAI0);
        const f16x8 aI1 = *(const f16x8*)(s + offAI1);
        const f16x8 bR  = *(const f16x8*)(s + offBR);
        const f16x8 bI  = *(const f16x8*)(s + offBI);
        const f16x8 bN  = *(const f16x8*)(s + offBN_);

        accRe0 = __builtin_amdgcn_mfma_f32_32x32x16_f16(aR0, bR, accRe0, 0, 0, 0);
        accRe0 = __builtin_amdgcn_mfma_f32_32x32x16_f16(aI0, bN, accRe0, 0, 0, 0);
        accIm0 = __builtin_amdgcn_mfma_f32_32x32x16_f16(aR0, bI, accIm0, 0, 0, 0);
        accIm0 = __builtin_amdgcn_mfma_f32_32x32x16_f16(aI0, bR, accIm0, 0, 0, 0);
        accRe1 = __builtin_amdgcn_mfma_f32_32x32x16_f16(aR1, bR, accRe1, 0, 0, 0);
        accRe1 = __builtin_amdgcn_mfma_f32_32x32x16_f16(aI1, bN, accRe1, 0, 0, 0);
        accIm1 = __builtin_amdgcn_mfma_f32_32x32x16_f16(aR1, bI, accIm1, 0, 0, 0);
        accIm1 = __builtin_amdgcn_mfma_f32_32x32x16_f16(aI1, bR, accIm1, 0, 0, 0);

        __syncthreads();
    }

    // ---- epilogue: out = Re^2 + Im^2 ----
    // C/D layout (32x32): col = lane&31, row = (reg&3) + 8*(reg>>2) + 4*(lane>>5)
    const int gn = n0 + wn * 32 + la;
    {
        const int gmBase = m0 + wm * 64;
        #pragma unroll
        for (int r = 0; r < 16; ++r) {
            const int row = (r & 3) + 8 * (r >> 2) + 4 * lg;
            const float er = accRe0[r], ei = accIm0[r];
            out[(size_t)(gmBase + row) * RES + gn] = er * er + ei * ei;
        }
        #pragma unroll
        for (int r = 0; r < 16; ++r) {
            const int row = (r & 3) + 8 * (r >> 2) + 4 * lg;
            const float er = accRe1[r], ei = accIm1[r];
            out[(size_t)(gmBase + 32 + row) * RES + gn] = er * er + ei * ei;
        }
    }
    #undef STAGE
}

// ---------------------------------------------------------------------------
// Fallback: direct brute force (only used if ws_size too small).
// ---------------------------------------------------------------------------
__global__ __launch_bounds__(256) void ewald_direct(
    const float* __restrict__ theta, const float* __restrict__ reA,
    const float* __restrict__ imA, const float* __restrict__ x0A,
    const float* __restrict__ y0A, const float* __restrict__ lsA,
    const float* __restrict__ X, const float* __restrict__ Y,
    float* __restrict__ out)
{
    __shared__ float kxs[NB], kys[NB], res[NB], ims[NB], pxs[NB], pys[NB], is2s[NB];
    const int t = threadIdx.x;
    if (t < NB) {
        const float th  = theta[t];
        const float sig = expf(lsA[t]) + 0.001f;
        kxs[t] = 50.0f * cosf(th);
        kys[t] = 50.0f * sinf(th);
        res[t] = reA[t];
        ims[t] = imA[t];
        pxs[t] = x0A[t];
        pys[t] = y0A[t];
        is2s[t] = 1.0f / (sig * sig);
    }
    __syncthreads();

    const size_t npix = (size_t)RES * RES;
    for (size_t idx = (size_t)blockIdx.x * blockDim.x + t; idx < npix;
         idx += (size_t)gridDim.x * blockDim.x) {
        const float xv = X[idx], yv = Y[idx];
        float er = 0.f, ei = 0.f;
        for (int b = 0; b < NB; ++b) {
            const float dx = xv - pxs[b], dy = yv - pys[b];
            const float env = __expf(-(dx * dx + dy * dy) * is2s[b]);
            const float ph = kxs[b] * xv + kys[b] * yv;
            float s, c;
            __sincosf(ph, &s, &c);
            er += env * (res[b] * c - ims[b] * s);
            ei += env * (res[b] * s + ims[b] * c);
        }
        out[idx] = er * er + ei * ei;
    }
}

// ---------------------------------------------------------------------------
extern "C" void kernel_launch(void* const* d_in, const int* in_sizes, int n_in,
                              void* d_out, int out_size, void* d_ws, size_t ws_size,
                              hipStream_t stream) {
    const float* theta = (const float*)d_in[0];
    const float* reA   = (const float*)d_in[1];
    const float* imA   = (const float*)d_in[2];
    const float* x0A   = (const float*)d_in[3];
    const float* y0A   = (const float*)d_in[4];
    const float* lsA   = (const float*)d_in[5];
    const float* X     = (const float*)d_in[6];
    const float* Y     = (const float*)d_in[7];
    float* out = (float*)d_out;

    const size_t tbl  = (size_t)RES * NB;          // elements per plane
    const size_t need = 5 * tbl * sizeof(f16);     // 5 MB

    if (ws_size >= need) {
        f16* ARe  = (f16*)d_ws;
        f16* AIm  = ARe  + tbl;
        f16* BRe  = AIm  + tbl;
        f16* BIm  = BRe  + tbl;
        f16* BImN = BIm  + tbl;

        beam_tables_f16<<<RES, NB, 0, stream>>>(theta, reA, imA, x0A, y0A, lsA,
                                                X, Y, ARe, AIm, BRe, BIm, BImN);

        ewald_mfma<<<256, 512, 0, stream>>>(ARe, AIm, BRe, BIm, BImN, out);
    } else {
        ewald_direct<<<2048, 256, 0, stream>>>(theta, reA, imA, x0A, y0A, lsA,
                                               X, Y, out);
    }
}

// Round 5
// 26.875 us; speedup vs baseline: 9.7432x; 1.1427x over previous
//
#include <hip/hip_runtime.h>
#include <math.h>

#define RES 2048
#define NB  256

typedef _Float16 f16;
typedef _Float16 f16x8 __attribute__((ext_vector_type(8)));
typedef float    f32x16 __attribute__((ext_vector_type(16)));

#define AS1 __attribute__((address_space(1)))
#define AS3 __attribute__((address_space(3)))

__device__ __forceinline__ void g2l16(const void* g, void* l) {
    // async 16B/lane global->LDS; LDS dest = wave-uniform base + lane*16
    __builtin_amdgcn_global_load_lds((const AS1 void*)g, (AS3 void*)l, 16, 0, 0);
}

__device__ __forceinline__ f16x8 neg8(f16x8 v) {
    union { f16x8 h; unsigned int u[4]; } x;
    x.h = v;
    #pragma unroll
    for (int i = 0; i < 4; ++i) x.u[i] ^= 0x80008000u;
    return x.h;
}

// ---------------------------------------------------------------------------
// Kernel 1: per-beam, per-axis complex tables, [pos][beam] layout, fp16.
//   A(i,b) = (re + i*im) * exp(-(x_i-x0)^2/s^2) * exp(i*kx*x_i)   (M side)
//   B(j,b) =               exp(-(y_j-y0)^2/s^2) * exp(i*ky*y_j)   (N side)
// Per-beam params computed ONCE per block into LDS; fast intrinsics.
// Grid: RES/8 blocks x NB threads; each block does 8 positions.
// ---------------------------------------------------------------------------
#define POSPB 8

__global__ __launch_bounds__(NB) void beam_tables_f16(
    const float* __restrict__ theta, const float* __restrict__ reA,
    const float* __restrict__ imA, const float* __restrict__ x0A,
    const float* __restrict__ y0A, const float* __restrict__ lsA,
    const float* __restrict__ X, const float* __restrict__ Y,
    f16* __restrict__ ARe, f16* __restrict__ AIm,
    f16* __restrict__ BRe, f16* __restrict__ BIm)
{
    __shared__ float skx[NB], sky[NB], sre[NB], sim[NB], spx[NB], spy[NB], sis2[NB];
    const int b = threadIdx.x;
    {
        float s, c;
        __sincosf(theta[b], &s, &c);
        skx[b] = 50.0f * c;
        sky[b] = 50.0f * s;
        const float sig = __expf(lsA[b]) + 0.001f;
        sis2[b] = 1.0f / (sig * sig);
        sre[b] = reA[b]; sim[b] = imA[b];
        spx[b] = x0A[b]; spy[b] = y0A[b];
    }
    __syncthreads();

    const float kx = skx[b], ky = sky[b];
    const float re = sre[b], im = sim[b];
    const float px = spx[b], py = spy[b];
    const float is2 = sis2[b];

    #pragma unroll
    for (int ii = 0; ii < POSPB; ++ii) {
        const int i = blockIdx.x * POSPB + ii;
        const float xv = X[(size_t)i * RES];  // X[i][0] = x_i (indexing='ij')
        const float yv = Y[i];                // Y[0][j] = y_j
        float sx, cx, sy, cy;
        __sincosf(kx * xv, &sx, &cx);
        __sincosf(ky * yv, &sy, &cy);
        const float dx = xv - px, dy = yv - py;
        const float ex = __expf(-dx * dx * is2);
        const float ey = __expf(-dy * dy * is2);
        const int o = i * NB + b;
        ARe[o] = (f16)(ex * (re * cx - im * sx));
        AIm[o] = (f16)(ex * (re * sx + im * cx));
        BRe[o] = (f16)(ey * cy);
        BIm[o] = (f16)(ey * sy);
    }
}

// ---------------------------------------------------------------------------
// Kernel 2: complex GEMM on matrix cores.  E[i,j] = sum_b A(i,b)*B(j,b).
// mfma_f32_32x32x16_f16, BM=BN=128, BK=16, 256 threads = 4 waves (2Mx2N),
// wave tile 64x64 (4 C-tiles, Re+Im accs = 128 acc VGPR).
// 4 LDS planes {ARe,AIm,BRe,BIm}; BIm negated in-register (exact).
// LDS: [2 buf][4 planes][128 rows][16 f16] = 32 KB, 2-phase double-buffer
// via global_load_lds (zero staging VGPRs), one barrier per k-tile.
// Per k-tile per wave: 8 ds_read_b128 + 16 MFMA.
// ---------------------------------------------------------------------------
#define BM 128
#define BN 128
#define BK 16
#define NKT (NB / BK)          // 16
#define PL  (BM * BK)          // elements per plane (2048)
#define BUFSTRIDE (4 * PL)

__global__ __launch_bounds__(256) void ewald_mfma(
    const f16* __restrict__ ARe, const f16* __restrict__ AIm,
    const f16* __restrict__ BRe, const f16* __restrict__ BIm,
    float* __restrict__ out)
{
    __shared__ f16 sm[2][4][BM][BK];
    f16* const smBase = &sm[0][0][0][0];

    const int t    = threadIdx.x;
    const int lane = t & 63;
    const int wave = t >> 6;       // 0..3
    const int wm   = wave >> 1;    // 0..1 -> M offset 64
    const int wn   = wave & 1;     // 0..1 -> N offset 64
    const int la   = lane & 31;
    const int lg   = lane >> 5;

    // XCD-aware swizzle (256 blocks, 8 XCDs -> 32 contiguous per XCD)
    const int flat = blockIdx.x;
    const int swz  = (flat & 7) * 32 + (flat >> 3);
    const int m0   = (swz >> 4) * BM;
    const int n0   = (swz & 15) * BN;

    // ---- staging map: 16 wave-loads (1 KB each) per k-tile, 4 per wave ----
    // q = wave + 4*j; plane p = q>>2 in {ARe,AIm,BRe,BIm}; chunk c = q&3
    // covers rows c*32..c*32+31; lane l -> row c*32 + (l>>1), k-half l&1.
    const f16* gsrc[4];
    int ldso[4];
    #pragma unroll
    for (int j = 0; j < 4; ++j) {
        const int q = wave + 4 * j;
        const int p = q >> 2;
        const int c = q & 3;
        const f16* tp = (p == 0) ? ARe : (p == 1) ? AIm : (p == 2) ? BRe : BIm;
        const int rowbase = ((p < 2) ? m0 : n0) + c * 32 + (lane >> 1);
        gsrc[j] = tp + (size_t)rowbase * NB + (lane & 1) * 8;
        ldso[j] = p * PL + c * 512;
    }

    #define STAGE(boff, kt)                                                   \
    do {                                                                      \
        _Pragma("unroll")                                                     \
        for (int j = 0; j < 4; ++j)                                           \
            g2l16(gsrc[j] + (kt) * BK, smBase + (boff) + ldso[j]);            \
    } while (0)

    // ---- fragment LDS element-offsets (within one buffer) ----
    // A row msub+la, k-half lg; sub s in {0,1} (rows +0 / +32)
    const int offA[2][2] = {
        { 0 * PL + (wm * 64 +  0 + la) * BK + lg * 8,
          0 * PL + (wm * 64 + 32 + la) * BK + lg * 8 },
        { 1 * PL + (wm * 64 +  0 + la) * BK + lg * 8,
          1 * PL + (wm * 64 + 32 + la) * BK + lg * 8 } };
    const int offB[2][2] = {
        { 2 * PL + (wn * 64 +  0 + la) * BK + lg * 8,
          2 * PL + (wn * 64 + 32 + la) * BK + lg * 8 },
        { 3 * PL + (wn * 64 +  0 + la) * BK + lg * 8,
          3 * PL + (wn * 64 + 32 + la) * BK + lg * 8 } };

    f32x16 accRe[2][2] = { { (f32x16)0.0f, (f32x16)0.0f },
                           { (f32x16)0.0f, (f32x16)0.0f } };
    f32x16 accIm[2][2] = { { (f32x16)0.0f, (f32x16)0.0f },
                           { (f32x16)0.0f, (f32x16)0.0f } };

    // ---- prologue ----
    STAGE(0, 0);
    __syncthreads();

    for (int kt = 0; kt < NKT; ++kt) {
        const int boff = (kt & 1) * BUFSTRIDE;
        if (kt + 1 < NKT)
            STAGE(((kt + 1) & 1) * BUFSTRIDE, kt + 1);

        const f16* s = smBase + boff;
        f16x8 aR[2], aI[2], bR[2], bI[2], bN[2];
        #pragma unroll
        for (int x = 0; x < 2; ++x) {
            aR[x] = *(const f16x8*)(s + offA[0][x]);
            aI[x] = *(const f16x8*)(s + offA[1][x]);
            bR[x] = *(const f16x8*)(s + offB[0][x]);
            bI[x] = *(const f16x8*)(s + offB[1][x]);
            bN[x] = neg8(bI[x]);
        }

        #pragma unroll
        for (int ms = 0; ms < 2; ++ms) {
            #pragma unroll
            for (int ns = 0; ns < 2; ++ns) {
                accRe[ms][ns] = __builtin_amdgcn_mfma_f32_32x32x16_f16(
                    aR[ms], bR[ns], accRe[ms][ns], 0, 0, 0);
                accRe[ms][ns] = __builtin_amdgcn_mfma_f32_32x32x16_f16(
                    aI[ms], bN[ns], accRe[ms][ns], 0, 0, 0);
                accIm[ms][ns] = __builtin_amdgcn_mfma_f32_32x32x16_f16(
                    aR[ms], bI[ns], accIm[ms][ns], 0, 0, 0);
                accIm[ms][ns] = __builtin_amdgcn_mfma_f32_32x32x16_f16(
                    aI[ms], bR[ns], accIm[ms][ns], 0, 0, 0);
            }
        }
        __syncthreads();
    }

    // ---- epilogue: out = Re^2 + Im^2 ----
    // C/D layout (32x32): col = lane&31, row = (reg&3) + 8*(reg>>2) + 4*(lane>>5)
    #pragma unroll
    for (int ms = 0; ms < 2; ++ms) {
        #pragma unroll
        for (int ns = 0; ns < 2; ++ns) {
            const int gmBase = m0 + wm * 64 + ms * 32;
            const int gn     = n0 + wn * 64 + ns * 32 + la;
            #pragma unroll
            for (int r = 0; r < 16; ++r) {
                const int row = (r & 3) + 8 * (r >> 2) + 4 * lg;
                const float er = accRe[ms][ns][r], ei = accIm[ms][ns][r];
                out[(size_t)(gmBase + row) * RES + gn] = er * er + ei * ei;
            }
        }
    }
    #undef STAGE
}

// ---------------------------------------------------------------------------
// Fallback: direct brute force (only used if ws_size too small).
// ---------------------------------------------------------------------------
__global__ __launch_bounds__(256) void ewald_direct(
    const float* __restrict__ theta, const float* __restrict__ reA,
    const float* __restrict__ imA, const float* __restrict__ x0A,
    const float* __restrict__ y0A, const float* __restrict__ lsA,
    const float* __restrict__ X, const float* __restrict__ Y,
    float* __restrict__ out)
{
    __shared__ float kxs[NB], kys[NB], res[NB], ims[NB], pxs[NB], pys[NB], is2s[NB];
    const int t = threadIdx.x;
    if (t < NB) {
        const float th  = theta[t];
        const float sig = expf(lsA[t]) + 0.001f;
        kxs[t] = 50.0f * cosf(th);
        kys[t] = 50.0f * sinf(th);
        res[t] = reA[t];
        ims[t] = imA[t];
        pxs[t] = x0A[t];
        pys[t] = y0A[t];
        is2s[t] = 1.0f / (sig * sig);
    }
    __syncthreads();

    const size_t npix = (size_t)RES * RES;
    for (size_t idx = (size_t)blockIdx.x * blockDim.x + t; idx < npix;
         idx += (size_t)gridDim.x * blockDim.x) {
        const float xv = X[idx], yv = Y[idx];
        float er = 0.f, ei = 0.f;
        for (int b = 0; b < NB; ++b) {
            const float dx = xv - pxs[b], dy = yv - pys[b];
            const float env = __expf(-(dx * dx + dy * dy) * is2s[b]);
            const float ph = kxs[b] * xv + kys[b] * yv;
            float s, c;
            __sincosf(ph, &s, &c);
            er += env * (res[b] * c - ims[b] * s);
            ei += env * (res[b] * s + ims[b] * c);
        }
        out[idx] = er * er + ei * ei;
    }
}

// ---------------------------------------------------------------------------
extern "C" void kernel_launch(void* const* d_in, const int* in_sizes, int n_in,
                              void* d_out, int out_size, void* d_ws, size_t ws_size,
                              hipStream_t stream) {
    const float* theta = (const float*)d_in[0];
    const float* reA   = (const float*)d_in[1];
    const float* imA   = (const float*)d_in[2];
    const float* x0A   = (const float*)d_in[3];
    const float* y0A   = (const float*)d_in[4];
    const float* lsA   = (const float*)d_in[5];
    const float* X     = (const float*)d_in[6];
    const float* Y     = (const float*)d_in[7];
    float* out = (float*)d_out;

    const size_t tbl  = (size_t)RES * NB;          // elements per plane
    const size_t need = 4 * tbl * sizeof(f16);     // 4 MB

    if (ws_size >= need) {
        f16* ARe = (f16*)d_ws;
        f16* AIm = ARe + tbl;
        f16* BRe = AIm + tbl;
        f16* BIm = BRe + tbl;

        beam_tables_f16<<<RES / POSPB, NB, 0, stream>>>(
            theta, reA, imA, x0A, y0A, lsA, X, Y, ARe, AIm, BRe, BIm);

        ewald_mfma<<<256, 256, 0, stream>>>(ARe, AIm, BRe, BIm, out);
    } else {
        ewald_direct<<<2048, 256, 0, stream>>>(theta, reA, imA, x0A, y0A, lsA,
                                               X, Y, out);
    }
}